// Round 7
// baseline (196.335 us; speedup 1.0000x reference)
//
#include <hip/hip_runtime.h>
#include <math.h>

#define N_ROWS 4096
#define D_DIM  256
#define INV_T  (1.0f / 0.07f)

typedef _Float16 half8 __attribute__((ext_vector_type(8)));
typedef _Float16 half4 __attribute__((ext_vector_type(4)));
typedef float    f32x4 __attribute__((ext_vector_type(4)));

#define GLOAD_LDS(gp, lp) \
    __builtin_amdgcn_global_load_lds( \
        (const __attribute__((address_space(1))) void*)(gp), \
        (__attribute__((address_space(3))) void*)(lp), 16, 0, 0)

// ---------------------------------------------------------------------------
// K1: row-normalize features -> fp16 (one wave per row) + zero accum.
// ---------------------------------------------------------------------------
__global__ __launch_bounds__(256) void normalize_k(const float* __restrict__ f,
                                                   _Float16* __restrict__ fnh,
                                                   float* __restrict__ accum) {
    const int t   = threadIdx.x;
    const int gid = blockIdx.x * 256 + t;
    if (gid < 3 * N_ROWS) accum[gid] = 0.0f;

    const int lane = t & 63;
    const int row  = blockIdx.x * 4 + (t >> 6);
    float4 v = ((const float4*)(f + (size_t)row * D_DIM))[lane];
    float s = v.x * v.x + v.y * v.y + v.z * v.z + v.w * v.w;
    #pragma unroll
    for (int off = 32; off > 0; off >>= 1) s += __shfl_xor(s, off, 64);
    float rn = 1.0f / fmaxf(sqrtf(s), 1e-8f);
    half4 h;
    h.x = (_Float16)(v.x * rn);
    h.y = (_Float16)(v.y * rn);
    h.z = (_Float16)(v.z * rn);
    h.w = (_Float16)(v.w * rn);
    *(half4*)(fnh + (size_t)row * D_DIM + lane * 4) = h;
}

// ---------------------------------------------------------------------------
// K2: producer/consumer fused kernel. 512 threads = 8 waves, tile 128x128.
//   Waves 0-3 (GEMM): round-4 MFMA K-loop (BK=64, XOR-swizzled LDS staging
//     via global_load_lds), then dump cs=acc*INV_T (fp16) into the As/Bs
//     region (dead after the K-loop).
//   Waves 4-7 (streamers): concurrently stream this tile's pm/nm (128 KB
//     fp32 global), pack to 2-bit mask bytes (pm|nm<<1) in a disjoint 16 KB
//     LDS region. Mask HBM traffic overlaps the MFMA work entirely.
//   Barriers are textually shared (single loop, role branches inside).
//   Epilogue: all 8 waves read cs(fp16)+mask bytes from LDS, reduce 3
//     per-row scalars, 2 shuffles + 3 atomics per row.
// LDS: 32 KB As/Bs (-> cs) + 16 KB packed masks = 48 KB -> 3 blocks/CU.
// ---------------------------------------------------------------------------
__global__ __launch_bounds__(512) void fused2_k(const _Float16* __restrict__ fnh,
                                                const float* __restrict__ pm,
                                                const float* __restrict__ nm,
                                                float* __restrict__ accum) {
    __shared__ __align__(16) char smem[49152];
    _Float16* As = (_Float16*)smem;              // [128][64] halfs, 16 KB
    _Float16* Bs = (_Float16*)(smem + 16384);    // [128][64] halfs, 16 KB
    char*     mk = smem + 32768;                 // packed masks, 128 x 128 B
    // cs (post-K-loop) reuses smem[0..32768): row*256 B, 16B granule swizzle.

    const int t    = threadIdx.x;
    const int lane = t & 63;
    const int i0   = blockIdx.y * 128;
    const int j0   = blockIdx.x * 128;

    const bool is_gemm = (t < 256);

    // --- GEMM-wave identifiers (valid when t<256) ---
    const int w    = t >> 6;          // 0..3
    const int wr   = w >> 1;
    const int wc   = w & 1;
    const int l15  = lane & 15;
    const int grp  = lane >> 4;
    const int srow = t >> 3;                          // 0..31
    const int sseg = ((t & 7) ^ ((t >> 3) & 7)) * 8;  // swizzled 16B granule

    // --- streamer identifiers (valid when t>=256) ---
    const int ts = t & 255;           // 0..255
    const int lr = ts & 7;            // 8 lanes per mask row

    f32x4 acc[4][4];  // [jt][it]
    #pragma unroll
    for (int a = 0; a < 4; ++a)
        #pragma unroll
        for (int b = 0; b < 4; ++b)
            acc[a][b] = (f32x4){0.f, 0.f, 0.f, 0.f};

    #pragma unroll
    for (int p = 0; p < 4; ++p) {
        f32x4 pv[4], nv[4];
        if (is_gemm) {
            const int k0 = p * 64;
            #pragma unroll
            for (int q = 0; q < 4; ++q) {
                GLOAD_LDS(fnh + (size_t)(i0 + q * 32 + srow) * D_DIM + k0 + sseg,
                          &As[q * 2048 + w * 512]);
                GLOAD_LDS(fnh + (size_t)(j0 + q * 32 + srow) * D_DIM + k0 + sseg,
                          &Bs[q * 2048 + w * 512]);
            }
        } else {
            const int r  = p * 32 + (ts >> 3);
            const f32x4* pp = (const f32x4*)(pm + (size_t)(i0 + r) * N_ROWS + j0 + lr * 16);
            const f32x4* np_ = (const f32x4*)(nm + (size_t)(i0 + r) * N_ROWS + j0 + lr * 16);
            #pragma unroll
            for (int q = 0; q < 4; ++q) pv[q] = __builtin_nontemporal_load(pp + q);
            #pragma unroll
            for (int q = 0; q < 4; ++q) nv[q] = __builtin_nontemporal_load(np_ + q);
        }
        __syncthreads();
        if (is_gemm) {
            #pragma unroll
            for (int kk = 0; kk < 2; ++kk) {
                const int swz = ((kk * 4 + grp) ^ (l15 & 7)) * 8;
                half8 aj[4], bi[4];
                #pragma unroll
                for (int jt = 0; jt < 4; ++jt)
                    aj[jt] = *(const half8*)&Bs[(wc * 64 + jt * 16 + l15) * 64 + swz];
                #pragma unroll
                for (int it = 0; it < 4; ++it)
                    bi[it] = *(const half8*)&As[(wr * 64 + it * 16 + l15) * 64 + swz];
                #pragma unroll
                for (int jt = 0; jt < 4; ++jt)
                    #pragma unroll
                    for (int it = 0; it < 4; ++it)
                        acc[jt][it] = __builtin_amdgcn_mfma_f32_16x16x32_f16(
                            aj[jt], bi[it], acc[jt][it], 0, 0, 0);
            }
        } else {
            const int r = p * 32 + (ts >> 3);
            uint4 wv;
            unsigned wd[4];
            #pragma unroll
            for (int q = 0; q < 4; ++q) {
                unsigned b0 = (pv[q].x != 0.f ? 1u : 0u) | (nv[q].x != 0.f ? 2u : 0u);
                unsigned b1 = (pv[q].y != 0.f ? 1u : 0u) | (nv[q].y != 0.f ? 2u : 0u);
                unsigned b2 = (pv[q].z != 0.f ? 1u : 0u) | (nv[q].z != 0.f ? 2u : 0u);
                unsigned b3 = (pv[q].w != 0.f ? 1u : 0u) | (nv[q].w != 0.f ? 2u : 0u);
                wd[q] = b0 | (b1 << 8) | (b2 << 16) | (b3 << 24);
            }
            wv.x = wd[0]; wv.y = wd[1]; wv.z = wd[2]; wv.w = wd[3];
            *(uint4*)(mk + r * 128 + ((lr ^ (r & 7)) << 4)) = wv;
        }
        __syncthreads();
    }

    // GEMM waves: cs -> LDS (fp16, 16B-granule XOR swizzle g ^ (row&15)).
    if (is_gemm) {
        #pragma unroll
        for (int it = 0; it < 4; ++it) {
            const int row = wr * 64 + it * 16 + l15;
            #pragma unroll
            for (int jt = 0; jt < 4; ++jt) {
                half4 h;
                h.x = (_Float16)(acc[jt][it][0] * INV_T);
                h.y = (_Float16)(acc[jt][it][1] * INV_T);
                h.z = (_Float16)(acc[jt][it][2] * INV_T);
                h.w = (_Float16)(acc[jt][it][3] * INV_T);
                const int g   = wc * 8 + jt * 2 + (grp >> 1);
                const int off = ((g ^ l15) << 4) | ((grp & 1) << 3);
                *(half4*)(smem + row * 256 + off) = h;
            }
        }
    }
    __syncthreads();

    // Epilogue: 8 waves x 16 rows; 4 lanes/row, 32 cols each.
    {
        const int v = t >> 6;                 // wave 0..7
        const int r = v * 16 + (lane >> 2);   // tile-local row
        const int q = lane & 3;
        const int i = i0 + r;
        const int dloc = i - j0;              // diagonal position in col-space

        float negp = 0.f, posp = 0.f, np = 0.f;
        #pragma unroll
        for (int u = 0; u < 4; ++u) {
            const int c  = q * 32 + u * 8;
            const int g  = q * 4 + u;
            half8 h8 = *(const half8*)(smem + r * 256 + ((g ^ (r & 15)) << 4));
            const int gm = q * 2 + (u >> 1);
            uint2 mw = *(const uint2*)(mk + r * 128 + ((gm ^ (r & 7)) << 4) + (u & 1) * 8);
            #pragma unroll
            for (int e = 0; e < 8; ++e) {
                unsigned mm = (e < 4) ? (mw.x >> (e * 8)) : (mw.y >> ((e - 4) * 8));
                float pmb = (float)(mm & 1u);
                float nmb = (float)((mm >> 1) & 1u);
                float keep = (c + e == dloc) ? 0.f : 1.f;
                float csv = (float)h8[e];
                pmb *= keep;
                nmb *= keep;
                negp = fmaf(__expf(csv), nmb, negp);
                posp = fmaf(csv, pmb, posp);
                np  += pmb;
            }
        }
        negp += __shfl_xor(negp, 1, 64);
        posp += __shfl_xor(posp, 1, 64);
        np   += __shfl_xor(np,   1, 64);
        negp += __shfl_xor(negp, 2, 64);
        posp += __shfl_xor(posp, 2, 64);
        np   += __shfl_xor(np,   2, 64);
        if (q == 0) {
            atomicAdd(&accum[i], negp);
            atomicAdd(&accum[N_ROWS + i], posp);
            atomicAdd(&accum[2 * N_ROWS + i], np);
        }
    }
}

// ---------------------------------------------------------------------------
// K3: final reduction over rows -> scalar loss
// ---------------------------------------------------------------------------
__global__ __launch_bounds__(256) void final_k(const float* __restrict__ accum,
                                               float* __restrict__ out) {
    const int t = threadIdx.x;
    float s = 0.f;
    for (int i = t; i < N_ROWS; i += 256) {
        float neg  = accum[i];
        float posc = accum[N_ROWS + i];
        float np   = accum[2 * N_ROWS + i];
        float term = (np > 0.f) ? (posc - np * logf(fmaxf(neg, 1e-30f))) / np : 0.f;
        s += term;
    }
    #pragma unroll
    for (int off = 32; off > 0; off >>= 1) s += __shfl_xor(s, off, 64);
    __shared__ float wsum[4];
    if ((t & 63) == 0) wsum[t >> 6] = s;
    __syncthreads();
    if (t == 0) {
        float tot = wsum[0] + wsum[1] + wsum[2] + wsum[3];
        out[0] = -tot / (float)N_ROWS;
    }
}

// ---------------------------------------------------------------------------
extern "C" void kernel_launch(void* const* d_in, const int* in_sizes, int n_in,
                              void* d_out, int out_size, void* d_ws, size_t ws_size,
                              hipStream_t stream) {
    const float* feat = (const float*)d_in[0];
    const float* pm   = (const float*)d_in[1];
    const float* nm   = (const float*)d_in[2];
    float* out = (float*)d_out;

    _Float16* fnh = (_Float16*)d_ws;                          // 2 MB
    float* accum  = (float*)(fnh + (size_t)N_ROWS * D_DIM);   // 48 KB

    normalize_k<<<N_ROWS / 4, 256, 0, stream>>>(feat, fnh, accum);

    dim3 grid(N_ROWS / 128, N_ROWS / 128);
    fused2_k<<<grid, 512, 0, stream>>>(fnh, pm, nm, accum);

    final_k<<<1, 256, 0, stream>>>(accum, out);
}

// Round 8
// 175.690 us; speedup vs baseline: 1.1175x; 1.1175x over previous
//
#include <hip/hip_runtime.h>
#include <math.h>

#define N_ROWS 4096
#define D_DIM  256
#define INV_T  (1.0f / 0.07f)

typedef _Float16 half8 __attribute__((ext_vector_type(8)));
typedef _Float16 half4 __attribute__((ext_vector_type(4)));
typedef float    f32x4 __attribute__((ext_vector_type(4)));

#define GLOAD_LDS(gp, lp) \
    __builtin_amdgcn_global_load_lds( \
        (const __attribute__((address_space(1))) void*)(gp), \
        (__attribute__((address_space(3))) void*)(lp), 16, 0, 0)

// ---------------------------------------------------------------------------
// K1: row-normalize features -> fp16 (one wave per row) + zero accum.
// ---------------------------------------------------------------------------
__global__ __launch_bounds__(256) void normalize_k(const float* __restrict__ f,
                                                   _Float16* __restrict__ fnh,
                                                   float* __restrict__ accum) {
    const int t   = threadIdx.x;
    const int gid = blockIdx.x * 256 + t;
    if (gid < 3 * N_ROWS) accum[gid] = 0.0f;

    const int lane = t & 63;
    const int row  = blockIdx.x * 4 + (t >> 6);
    float4 v = ((const float4*)(f + (size_t)row * D_DIM))[lane];
    float s = v.x * v.x + v.y * v.y + v.z * v.z + v.w * v.w;
    #pragma unroll
    for (int off = 32; off > 0; off >>= 1) s += __shfl_xor(s, off, 64);
    float rn = 1.0f / fmaxf(sqrtf(s), 1e-8f);
    half4 h;
    h.x = (_Float16)(v.x * rn);
    h.y = (_Float16)(v.y * rn);
    h.z = (_Float16)(v.z * rn);
    h.w = (_Float16)(v.w * rn);
    *(half4*)(fnh + (size_t)row * D_DIM + lane * 4) = h;
}

// ---------------------------------------------------------------------------
// K2: fused MFMA cosim + LDS cs round-trip + coalesced mask streaming.
// Round 8: 64x64 tiles (4096 blocks, 16 KB LDS) so ~8 blocks/CU are resident
// out of 16/CU total -> staggered arrivals overlap one block's GEMM phase
// with other blocks' streaming phase (round 4's 128-tile grid was exactly
// resident-sized: GEMM ran in lockstep and its ~11 us was fully exposed).
// Internals identical to the verified round-4 kernel: XOR-swizzled LDS via
// global_load_lds (0 conflicts), swapped MFMA operands (i on l15 side),
// cs->LDS fp16, mask reads 256 B-contiguous per row-segment.
// ---------------------------------------------------------------------------
__global__ __launch_bounds__(256) void fused_k(const _Float16* __restrict__ fnh,
                                               const float* __restrict__ pm,
                                               const float* __restrict__ nm,
                                               float* __restrict__ accum) {
    __shared__ __align__(16) _Float16 lds[64 * 128];   // 16 KB
    _Float16* As = lds;             // [64][64] halfs during K-loop
    _Float16* Bs = lds + 64 * 64;   // [64][64] halfs during K-loop
    // cs (post-K-loop) reuses lds[0..4096): row*128 B, 16B-granule swizzle.

    const int t    = threadIdx.x;
    const int lane = t & 63;
    const int w    = t >> 6;        // wave 0..3
    const int wr   = w >> 1;        // i-half of tile
    const int wc   = w & 1;         // j-half of tile
    const int i0   = blockIdx.y * 64;
    const int j0   = blockIdx.x * 64;
    const int l15  = lane & 15;
    const int grp  = lane >> 4;

    // staging: 8 lanes-worth of granules per row, XOR-swizzled
    const int srow = t >> 3;                          // 0..31 per issue
    const int sslot = ((t & 7) ^ ((t >> 3) & 7)) * 8; // swizzled 16B granule (halfs)

    f32x4 acc[2][2];  // [jt][it]
    #pragma unroll
    for (int a = 0; a < 2; ++a)
        #pragma unroll
        for (int b = 0; b < 2; ++b)
            acc[a][b] = (f32x4){0.f, 0.f, 0.f, 0.f};

    for (int k0 = 0; k0 < D_DIM; k0 += 64) {
        #pragma unroll
        for (int q = 0; q < 2; ++q) {
            GLOAD_LDS(fnh + (size_t)(i0 + q * 32 + srow) * D_DIM + k0 + sslot,
                      &As[q * 2048 + w * 512]);
            GLOAD_LDS(fnh + (size_t)(j0 + q * 32 + srow) * D_DIM + k0 + sslot,
                      &Bs[q * 2048 + w * 512]);
        }
        __syncthreads();

        #pragma unroll
        for (int kk = 0; kk < 2; ++kk) {
            half8 aj[2], bi[2];
            #pragma unroll
            for (int jt = 0; jt < 2; ++jt) {
                const int r = wc * 32 + jt * 16 + l15;
                aj[jt] = *(const half8*)&Bs[r * 64 + (((kk * 4 + grp) ^ (r & 7)) << 3)];
            }
            #pragma unroll
            for (int it = 0; it < 2; ++it) {
                const int r = wr * 32 + it * 16 + l15;
                bi[it] = *(const half8*)&As[r * 64 + (((kk * 4 + grp) ^ (r & 7)) << 3)];
            }
            #pragma unroll
            for (int jt = 0; jt < 2; ++jt)
                #pragma unroll
                for (int it = 0; it < 2; ++it)
                    acc[jt][it] = __builtin_amdgcn_mfma_f32_16x16x32_f16(
                        aj[jt], bi[it], acc[jt][it], 0, 0, 0);
        }
        __syncthreads();
    }

    // cs -> LDS as fp16. (i_loc = wr*32+it*16+l15, j_loc = wc*32+jt*16+grp*4+reg)
    // Row = 128 B = 8 granules of 16 B; granule g stored at slot g^(row&7).
    #pragma unroll
    for (int it = 0; it < 2; ++it) {
        const int row = wr * 32 + it * 16 + l15;
        #pragma unroll
        for (int jt = 0; jt < 2; ++jt) {
            half4 h;
            h.x = (_Float16)(acc[jt][it][0] * INV_T);
            h.y = (_Float16)(acc[jt][it][1] * INV_T);
            h.z = (_Float16)(acc[jt][it][2] * INV_T);
            h.w = (_Float16)(acc[jt][it][3] * INV_T);
            const int g   = wc * 4 + jt * 2 + (grp >> 1);
            const int off = ((g ^ (row & 7)) << 4) | ((grp & 1) << 3);
            *(half4*)((char*)lds + row * 128 + off) = h;
        }
    }
    __syncthreads();

    // Mask streaming: step s covers rows s*16+lrow (lrow = t>>4), 16 lanes/row
    // each loading float4 -> 256 B contiguous per row-segment.
    const int lrow = t >> 4;   // 0..15
    const int lcol = t & 15;
    #pragma unroll
    for (int s = 0; s < 4; ++s) {
        const int r  = s * 16 + lrow;
        const int i  = i0 + r;
        const int jb = j0 + lcol * 4;
        float4 pmv = *(const float4*)(pm + (size_t)i * N_ROWS + jb);
        float4 nmv = *(const float4*)(nm + (size_t)i * N_ROWS + jb);
        half4 h = *(const half4*)((const char*)lds + r * 128 +
                                  ((((lcol >> 1) ^ (r & 7)) << 4) | ((lcol & 1) << 3)));
        float cse[4] = {(float)h.x, (float)h.y, (float)h.z, (float)h.w};
        float pme[4] = {pmv.x, pmv.y, pmv.z, pmv.w};
        float nme[4] = {nmv.x, nmv.y, nmv.z, nmv.w};
        float negp = 0.f, posp = 0.f, np = 0.f;
        #pragma unroll
        for (int e = 0; e < 4; ++e) {
            float keep = (i == jb + e) ? 0.f : 1.f;
            float p  = pme[e] * keep;
            float nv = nme[e] * keep;
            negp = fmaf(__expf(cse[e]), nv, negp);
            posp = fmaf(cse[e], p, posp);
            np  += p;
        }
        #pragma unroll
        for (int off = 1; off < 16; off <<= 1) {
            negp += __shfl_xor(negp, off, 64);
            posp += __shfl_xor(posp, off, 64);
            np   += __shfl_xor(np,   off, 64);
        }
        if (lcol == 0) {
            atomicAdd(&accum[i], negp);
            atomicAdd(&accum[N_ROWS + i], posp);
            atomicAdd(&accum[2 * N_ROWS + i], np);
        }
    }
}

// ---------------------------------------------------------------------------
// K3: final reduction over rows -> scalar loss
// ---------------------------------------------------------------------------
__global__ __launch_bounds__(256) void final_k(const float* __restrict__ accum,
                                               float* __restrict__ out) {
    const int t = threadIdx.x;
    float s = 0.f;
    for (int i = t; i < N_ROWS; i += 256) {
        float neg  = accum[i];
        float posc = accum[N_ROWS + i];
        float np   = accum[2 * N_ROWS + i];
        float term = (np > 0.f) ? (posc - np * logf(fmaxf(neg, 1e-30f))) / np : 0.f;
        s += term;
    }
    #pragma unroll
    for (int off = 32; off > 0; off >>= 1) s += __shfl_xor(s, off, 64);
    __shared__ float wsum[4];
    if ((t & 63) == 0) wsum[t >> 6] = s;
    __syncthreads();
    if (t == 0) {
        float tot = wsum[0] + wsum[1] + wsum[2] + wsum[3];
        out[0] = -tot / (float)N_ROWS;
    }
}

// ---------------------------------------------------------------------------
extern "C" void kernel_launch(void* const* d_in, const int* in_sizes, int n_in,
                              void* d_out, int out_size, void* d_ws, size_t ws_size,
                              hipStream_t stream) {
    const float* feat = (const float*)d_in[0];
    const float* pm   = (const float*)d_in[1];
    const float* nm   = (const float*)d_in[2];
    float* out = (float*)d_out;

    _Float16* fnh = (_Float16*)d_ws;                          // 2 MB
    float* accum  = (float*)(fnh + (size_t)N_ROWS * D_DIM);   // 48 KB

    normalize_k<<<N_ROWS / 4, 256, 0, stream>>>(feat, fnh, accum);

    dim3 grid(N_ROWS / 64, N_ROWS / 64);
    fused_k<<<grid, 256, 0, stream>>>(fnh, pm, nm, accum);

    final_k<<<1, 256, 0, stream>>>(accum, out);
}